// Round 3
// baseline (995.014 us; speedup 1.0000x reference)
//
#include <hip/hip_runtime.h>
#include <math.h>

#define CC 512
#define BB 8
#define TTOT 8192
#define LEN1 (TTOT - 2)   // 8190
#define LEN2 (TTOT - 4)   // 8188
#define GPRE 8
#define GPOST 24
#define PITCH (GPRE + TTOT + GPOST)   // 8224 rows per batch (t-major buffers)

typedef unsigned short u16;
typedef __bf16 v8bf __attribute__((ext_vector_type(8)));
typedef float v4f __attribute__((ext_vector_type(4)));

__device__ __forceinline__ u16 f2b(float f) {
    unsigned u = __float_as_uint(f);
    unsigned r = (u + 0x7FFFu + ((u >> 16) & 1u)) >> 16;
    return (u16)r;
}
__device__ __forceinline__ float b2f(u16 h) {
    return __uint_as_float(((unsigned)h) << 16);
}
__device__ __forceinline__ void ldsdma16(const void* g, void* l) {
    __builtin_amdgcn_global_load_lds(
        (const __attribute__((address_space(1))) unsigned int*)g,
        (__attribute__((address_space(3))) unsigned int*)l, 16, 0, 0);
}

// ---------------------------------------------------------------------------
// Weight prep: w[co][ci][3] f32 -> wr[k][co][ci] bf16
// ---------------------------------------------------------------------------
__global__ __launch_bounds__(256) void wprep_kernel(const float* __restrict__ w,
                                                    u16* __restrict__ wr)
{
    int idx = blockIdx.x * 256 + threadIdx.x;     // co*512 + ci
    int co = idx >> 9, ci = idx & 511;
    const float* s = w + (size_t)idx * 3;
#pragma unroll
    for (int k = 0; k < 3; ++k)
        wr[((size_t)k * CC + co) * CC + ci] = f2b(s[k]);
}

// ---------------------------------------------------------------------------
// Zero guard rows of a t-major buffer: rows [-GPRE,0) and [Lstart, Lstart+GPOST)
// ---------------------------------------------------------------------------
__global__ __launch_bounds__(256) void zguard_kernel(u16* xt0, int Lstart)
{
    int r = blockIdx.x;            // 0..31
    int b = blockIdx.y;
    int row = (r < GPRE) ? (r - GPRE) : (Lstart + (r - GPRE));
    u16* p = xt0 + ((size_t)b * PITCH + row) * CC;
    p[threadIdx.x] = 0;
    p[threadIdx.x + 256] = 0;
}

// ---------------------------------------------------------------------------
// Fused activation1d producing t-major bf16 (row0-based, pitch PITCH).
// ---------------------------------------------------------------------------
template<bool TMAJ>
__global__ __launch_bounds__(256) void actT_kernel(
    const void* __restrict__ xin_v,
    u16* __restrict__ yout,
    const float* __restrict__ up_w,
    const float* __restrict__ down_w,
    const float* __restrict__ alpha,
    const float* __restrict__ beta,
    int Lin)
{
    const int Lout = Lin - 2;
    const int smax = 2 * Lin - 4;
    const int tid = threadIdx.x;
    const int t0 = blockIdx.x * 128;
    const int c0 = blockIdx.y * 32;
    const int b  = blockIdx.z;

    __shared__ float xs[140 * 33];
    __shared__ float sb[266 * 33];

    if (!TMAJ) {
        const float* xcb = (const float*)xin_v + ((size_t)b * CC + c0) * Lin;
        int lane = tid & 63, w = tid >> 6;
#pragma unroll
        for (int rr = 0; rr < 8; ++rr) {
            int c = w * 8 + rr;
            const float* xr = xcb + (size_t)c * Lin;
            for (int i = lane; i < 139; i += 64) {
                int g = t0 - 4 + i;
                xs[i * 33 + c] = (g >= 0 && g < Lin) ? xr[g] : 0.0f;
            }
        }
    } else {
        const u16* xb = (const u16*)xin_v + (size_t)b * PITCH * CC + c0;
        int pr = tid & 15, rq = tid >> 4;
        for (int r0 = 0; r0 < 139; r0 += 16) {
            int row = r0 + rq;
            if (row < 139) {
                int t = t0 - 4 + row;
                const u16* gp = xb + (ptrdiff_t)t * CC + pr * 2;
                ushort2 u = *(const ushort2*)gp;
                xs[row * 33 + pr * 2]     = b2f(u.x);
                xs[row * 33 + pr * 2 + 1] = b2f(u.y);
            }
        }
    }
    __syncthreads();

    {
        int c = tid & 31, sg = tid >> 5;
        int cg = c0 + c;
        float a     = expf(alpha[cg]);
        float inv2b = 1.0f / (2.0f * expf(beta[cg]) + 1e-9f);
        float uwa[6], uwb[6];
#pragma unroll
        for (int k = 0; k < 6; ++k) {
            uwa[k] = up_w[(2 * cg) * 6 + k];
            uwb[k] = up_w[(2 * cg + 1) * 6 + k];
        }
        const int s_lo = 2 * t0 - 5;
        for (int sl = sg; sl < 266; sl += 8) {
            int s = s_lo + sl;
            float v = 0.0f;
            if (s >= 0 && s < smax) {
                int sp = s + 2;
                int r  = sp & 1;
                int tt = sp >> 1;
                int xi = tt - t0 + 2;
                float u = 0.0f;
#pragma unroll
                for (int k = 0; k < 6; ++k) {
                    float wk = r ? uwb[k] : uwa[k];
                    u = fmaf(xs[(xi + k) * 33 + c], wk, u);
                }
                v = fmaf(1.0f - __cosf(2.0f * a * u), inv2b, u);
            }
            sb[sl * 33 + c] = v;
        }
    }
    __syncthreads();

    {
        int c = tid & 31, tg = tid >> 5;
        int cg = c0 + c;
        float dw[12];
#pragma unroll
        for (int j = 0; j < 12; ++j) dw[j] = down_w[cg * 12 + j];
        u16* yb = yout + (size_t)b * PITCH * CC;
        for (int tl = tg; tl < 128; tl += 8) {
            float y = 0.0f;
#pragma unroll
            for (int j = 0; j < 12; ++j)
                y = fmaf(sb[(2 * tl + j) * 33 + c], dw[j], y);
            int t = t0 + tl;
            if (t < Lout) yb[(size_t)t * CC + cg] = f2b(y);
        }
    }
}

// ---------------------------------------------------------------------------
// k=3 pad=1 conv as bf16 MFMA GEMM over t-major input.
// Tile 256 t x 128 co. 4 waves, each 128t x 64co (8x4 MFMA tiles).
// X: double-buffered LDS (ldsdma), one barrier per 32-ci chunk, staging for
// chunk i+1 issued before MFMA(i) so the barrier drain is hidden.
// W: direct global->VGPR, register double-buffered (L2-resident, 1.5 MB).
// ---------------------------------------------------------------------------
#define XROWS 264
#define XBUF (4 * XROWS * 8)   // u16 elems per buffer

template<int ORIENT>
__global__ __launch_bounds__(256) void convg_kernel(
    const u16* __restrict__ xt,
    const u16* __restrict__ wr,     // [3][512][512] bf16
    const float* __restrict__ bias,
    u16* __restrict__ yt,
    float* __restrict__ out,
    const float* __restrict__ resid,
    int Lout)
{
    const int tid  = threadIdx.x;
    const int lane = tid & 63, wid = tid >> 6;
    const int wt = wid & 1, wc = wid >> 1;
    const int l15 = lane & 15, q = lane >> 4;
    const int t0  = blockIdx.x * 256;
    const int co0 = blockIdx.y * 128;
    const int b   = blockIdx.z;

    __shared__ __align__(16) u16 xsm[2 * XBUF];

    const u16* xb = xt + (size_t)b * PITCH * CC;
    const u16* wbase = wr + (size_t)(co0 + wc * 64 + l15) * CC + q * 8;

    v4f acc[8][4];
#pragma unroll
    for (int m = 0; m < 8; ++m)
#pragma unroll
        for (int n = 0; n < 4; ++n)
#pragma unroll
            for (int r = 0; r < 4; ++r) acc[m][n][r] = 0.0f;

    v8bf wA[12], wB[12];

#define LOADW(dst, ci0base) do {                                         \
    const u16* wp_ = wbase + (ci0base);                                  \
    _Pragma("unroll") for (int k_ = 0; k_ < 3; ++k_)                     \
    _Pragma("unroll") for (int n_ = 0; n_ < 4; ++n_)                     \
        dst[k_ * 4 + n_] = *(const v8bf*)(wp_ + k_ * 262144 + n_ * 8192);\
} while (0)

#define STAGEX(par, ci0base) do {                                        \
    u16* xsl_ = xsm + (par) * XBUF;                                      \
    for (int ii_ = wid; ii_ < 17; ii_ += 4) {                            \
        int task_ = ii_ * 64 + lane;                                     \
        if (task_ < 4 * XROWS) {                                         \
            int g_   = task_ / XROWS;                                    \
            int row_ = task_ - g_ * XROWS;                               \
            const u16* gp_ = xb + (ptrdiff_t)(t0 - 1 + row_) * CC        \
                             + (ci0base) + g_ * 8;                       \
            ldsdma16(gp_, xsl_ + ii_ * 64 * 8);                          \
        }                                                                \
    }                                                                    \
} while (0)

#define MFMA_CHUNK(par, wreg) do {                                       \
    const u16* xsl_ = xsm + (par) * XBUF;                                \
    _Pragma("unroll") for (int k_ = 0; k_ < 3; ++k_) {                   \
        _Pragma("unroll") for (int m_ = 0; m_ < 8; ++m_) {               \
            int r_ = wt * 128 + m_ * 16 + l15 + k_;                      \
            v8bf xf_ = *(const v8bf*)(xsl_ + ((q * XROWS) + r_) * 8);    \
            _Pragma("unroll") for (int n_ = 0; n_ < 4; ++n_) {           \
                if (ORIENT == 0)                                         \
                    acc[m_][n_] = __builtin_amdgcn_mfma_f32_16x16x32_bf16(\
                        xf_, wreg[k_ * 4 + n_], acc[m_][n_], 0, 0, 0);   \
                else                                                     \
                    acc[m_][n_] = __builtin_amdgcn_mfma_f32_16x16x32_bf16(\
                        wreg[k_ * 4 + n_], xf_, acc[m_][n_], 0, 0, 0);   \
            }                                                            \
        }                                                                \
    }                                                                    \
} while (0)

    LOADW(wA, 0);
    STAGEX(0, 0);

    for (int j = 0; j < 8; ++j) {
        const int i0 = 2 * j;
        __syncthreads();                       // X(i0) ready
        if (i0 + 1 < 16) {
            LOADW(wB, (i0 + 1) * 32);
            STAGEX(1, (i0 + 1) * 32);
        }
        MFMA_CHUNK(0, wA);
        __syncthreads();                       // X(i0+1) ready
        if (i0 + 2 < 16) {
            LOADW(wA, (i0 + 2) * 32);
            STAGEX(0, (i0 + 2) * 32);
        }
        MFMA_CHUNK(1, wB);
    }

#undef LOADW
#undef STAGEX
#undef MFMA_CHUNK

    if (ORIENT == 0) {
        float bv[4];
#pragma unroll
        for (int n = 0; n < 4; ++n) bv[n] = bias[co0 + wc * 64 + n * 16 + l15];
        u16* yb = yt + (size_t)b * PITCH * CC;
#pragma unroll
        for (int m = 0; m < 8; ++m) {
            int tb = t0 + wt * 128 + m * 16;
#pragma unroll
            for (int rg = 0; rg < 4; ++rg) {
                int t = tb + q * 4 + rg;
                if (t < Lout) {
#pragma unroll
                    for (int n = 0; n < 4; ++n) {
                        int co = co0 + wc * 64 + n * 16 + l15;
                        yb[(size_t)t * CC + co] = f2b(acc[m][n][rg] + bv[n]);
                    }
                }
            }
        }
    } else {
        float bv[4][4];
#pragma unroll
        for (int n = 0; n < 4; ++n)
#pragma unroll
            for (int rg = 0; rg < 4; ++rg)
                bv[n][rg] = bias[co0 + wc * 64 + n * 16 + q * 4 + rg];
#pragma unroll
        for (int n = 0; n < 4; ++n) {
#pragma unroll
            for (int rg = 0; rg < 4; ++rg) {
                int co = co0 + wc * 64 + n * 16 + q * 4 + rg;
                float* orow = out + ((size_t)b * CC + co) * Lout;
                const float* rrow = resid + ((size_t)b * CC + co) * TTOT;
#pragma unroll
                for (int m = 0; m < 8; ++m) {
                    int t = t0 + wt * 128 + m * 16 + l15;
                    if (t < Lout)
                        orow[t] = acc[m][n][rg] + bv[n][rg] + rrow[t];
                }
            }
        }
    }
}

// ---------------------------------------------------------------------------
extern "C" void kernel_launch(void* const* d_in, const int* in_sizes, int n_in,
                              void* d_out, int out_size, void* d_ws, size_t ws_size,
                              hipStream_t stream)
{
    const float* x       = (const float*)d_in[0];
    const float* up_w1   = (const float*)d_in[1];
    const float* down_w1 = (const float*)d_in[2];
    const float* alpha1  = (const float*)d_in[3];
    const float* beta1   = (const float*)d_in[4];
    const float* up_w2   = (const float*)d_in[5];
    const float* down_w2 = (const float*)d_in[6];
    const float* alpha2  = (const float*)d_in[7];
    const float* beta2   = (const float*)d_in[8];
    const float* c1_w    = (const float*)d_in[9];
    const float* c1_b    = (const float*)d_in[10];
    const float* c2_w    = (const float*)d_in[11];
    const float* c2_b    = (const float*)d_in[12];
    float* out = (float*)d_out;

    u16* wr1  = (u16*)d_ws;
    u16* wr2  = wr1 + 786432;
    u16* xTa0 = wr2 + 786432;
    u16* xTa  = xTa0 + GPRE * CC;
    u16* xTb0 = xTa0 + (size_t)BB * PITCH * CC;
    u16* xTb  = xTb0 + GPRE * CC;

    wprep_kernel<<<1024, 256, 0, stream>>>(c1_w, wr1);
    wprep_kernel<<<1024, 256, 0, stream>>>(c2_w, wr2);
    zguard_kernel<<<dim3(32, 8), 256, 0, stream>>>(xTa, LEN1);
    zguard_kernel<<<dim3(32, 8), 256, 0, stream>>>(xTb, LEN1);

    actT_kernel<false><<<dim3(64, 16, 8), 256, 0, stream>>>(
        (const void*)x, xTa, up_w1, down_w1, alpha1, beta1, TTOT);
    convg_kernel<0><<<dim3(32, 4, 8), 256, 0, stream>>>(
        xTa, wr1, c1_b, xTb, nullptr, nullptr, LEN1);
    zguard_kernel<<<dim3(32, 8), 256, 0, stream>>>(xTa, LEN2);
    actT_kernel<true><<<dim3(64, 16, 8), 256, 0, stream>>>(
        (const void*)xTb, xTa, up_w2, down_w2, alpha2, beta2, LEN1);
    convg_kernel<1><<<dim3(32, 4, 8), 256, 0, stream>>>(
        xTa, wr2, c2_b, nullptr, out, x, LEN2);
}